// Round 1
// baseline (116.575 us; speedup 1.0000x reference)
//
#include <hip/hip_runtime.h>

// DWT1D Haar analysis, B=32, N=4096, C=64.
// Key identity: with A the Haar analysis bank (2-tap, stride-2, no wrap for L=2),
//   out[b,k,0:C]   = l0*x[b,2k,:] + l1*x[b,2k+1,:]
//   out[b,k,C:2C]  = h0*x[b,2k,:] + h1*x[b,2k+1,:]
// and in flat float4 space the input chunk {bk*32 + c4, bk*32 + 16 + c4}
// maps to the output chunk at the SAME flat offsets (L half, H half).
// Pure streaming butterfly: 33.5 MB read + 33.5 MB write, memory-bound.

__global__ __launch_bounds__(256) void dwt1d_haar_kernel(
    const float4* __restrict__ x4,
    const float* __restrict__ A,
    float4* __restrict__ out4,
    long long halfN_row,   // half * N  (flat index of A[half,0])
    int total)             // number of threads = out_size/8
{
    int t = blockIdx.x * blockDim.x + threadIdx.x;
    if (t >= total) return;

    // Filter taps from A (wave-uniform scalar loads; L1/L2 broadcast).
    const float l0 = A[0];              // A[0,0]
    const float l1 = A[1];              // A[0,1]
    const float h0 = A[halfN_row];      // A[half,0]
    const float h1 = A[halfN_row + 1];  // A[half,1]

    const int c4 = t & 15;       // which float4 within the 64-float channel row
    const int bk = t >> 4;       // b*half + k  (pair-row index)

    const long long idx0 = (long long)bk * 32 + c4;  // row 2k   (float4 units)
    const long long idx1 = idx0 + 16;                // row 2k+1

    const float4 x0 = x4[idx0];
    const float4 x1 = x4[idx1];

    float4 lo, hi;
    lo.x = l0 * x0.x + l1 * x1.x;
    lo.y = l0 * x0.y + l1 * x1.y;
    lo.z = l0 * x0.z + l1 * x1.z;
    lo.w = l0 * x0.w + l1 * x1.w;
    hi.x = h0 * x0.x + h1 * x1.x;
    hi.y = h0 * x0.y + h1 * x1.y;
    hi.z = h0 * x0.z + h1 * x1.z;
    hi.w = h0 * x0.w + h1 * x1.w;

    out4[idx0] = lo;   // L band -> out[b,k,0:C]
    out4[idx1] = hi;   // H band -> out[b,k,C:2C]
}

extern "C" void kernel_launch(void* const* d_in, const int* in_sizes, int n_in,
                              void* d_out, int out_size, void* d_ws, size_t ws_size,
                              hipStream_t stream) {
    const float* x = (const float*)d_in[0];
    const float* A = (const float*)d_in[1];
    float* out = (float*)d_out;

    // N from A's element count (N*N). Setup gives N=4096.
    long long asz = in_sizes[1];
    long long N = 1;
    while (N * N < asz) N <<= 1;
    const long long half = N / 2;

    const int total = out_size / 8;  // each thread produces 8 output floats
    const int block = 256;
    const int grid = (total + block - 1) / block;

    dwt1d_haar_kernel<<<grid, block, 0, stream>>>(
        (const float4*)x, A, (float4*)out, half * N, total);
}